// Round 1
// baseline (34367.169 us; speedup 1.0000x reference)
//
#include <hip/hip_runtime.h>
#include <hip/hip_bf16.h>

// TimeGAN generator: 3-layer GRU (H=256) + feedback MLP, B=2048, T=256.
// Design: batch-parallel, zero grid syncs. 128 blocks x 16 rows; each block
// keeps h0/h1/h2 in LDS (fp32 master + bf16 copy) across all 256 steps and
// streams bf16-packed weights from L2 per step. mfma_f32_16x16x32_bf16.

typedef __attribute__((ext_vector_type(8))) short short8;   // 8 x bf16
typedef __attribute__((ext_vector_type(4))) float f32x4;

#define BQ   16      // batch rows per block
#define NTHR 512     // 8 waves
#define TT   256     // seq_len
#define NBLK 128     // 2048 / 16

// packed-weight fragment bases (in 64-lane-frag units; elements = frag*8)
#define FB_WI0  0        // [768 x  64], KT=2
#define FB_WH0  6144     // [768 x 256], KT=8
#define FB_WI1  30720
#define FB_WH1  55296
#define FB_WI2  79872
#define FB_WH2  104448
#define FB_W1   129024   // [256 x 256]
#define FB_W2   137216   // [ 64 x 256]
#define TOTAL_FRAGS 139264

__device__ __forceinline__ short bf16_rne(float v) {
  union { float f; unsigned u; } c; c.f = v;
  unsigned u = c.u;
  u += 0x7FFFu + ((u >> 16) & 1u);
  return (short)(u >> 16);
}
__device__ __forceinline__ float fast_sigmoid(float x) {
  return 1.0f / (1.0f + __expf(-x));
}
__device__ __forceinline__ float fast_tanh(float x) {
  // stable at both tails: exp(2x)->inf gives 1, exp(2x)->0 gives -1
  return 1.0f - 2.0f / (__expf(2.0f * x) + 1.0f);
}

// A-fragment read from a bf16 LDS tile [BQ][S] with XOR swizzle
// swizzle: element index (k) XOR'ed with (row&7)<<3  (16B granularity)
__device__ __forceinline__ short8 lds_a(const short* buf, int S, int row, int k) {
  int idx = row * S + (k ^ ((row & 7) << 3));
  return *(const short8*)(buf + idx);
}

struct CB { float brz0, brz1, bzz0, bzz1, bin0, bin1, bhn0, bhn1; };

__device__ __forceinline__ CB make_cb(const float* bi, const float* bh, int wave, int l15) {
  CB cb;
  int c0 = wave * 32 + l15, c1 = c0 + 16;
  cb.brz0 = bi[c0] + bh[c0];
  cb.brz1 = bi[c1] + bh[c1];
  cb.bzz0 = bi[256 + c0] + bh[256 + c0];
  cb.bzz1 = bi[256 + c1] + bh[256 + c1];
  cb.bin0 = bi[512 + c0];
  cb.bin1 = bi[512 + c1];
  cb.bhn0 = bh[512 + c0];
  cb.bhn1 = bh[512 + c1];
  return cb;
}

// One GRU cell for this block's 16 rows. gi = x @ Wi^T, gh = h @ Wh^T (both
// N=768 split 8 waves x (32 cols/gate chunk)); elementwise gate math in regs;
// writes h' to fp32 master + bf16 (swizzled) copy.
template<int KT_GI>
__device__ __forceinline__ void gru_cell(
    const short* gi_src, int gi_S,       // bf16 LDS input x (or h_{l-1})
    const short* gh_src,                 // bf16 LDS h_l (old)
    const short* __restrict__ wpack, int fbWi, int fbWh,
    float* hf_l, short* hb_l,            // fp32 master + bf16 copy of h_l
    CB cb, int wave, int lane)
{
  const int l15 = lane & 15, lhi = lane >> 4, r0 = lhi * 4;
  f32x4 zero4 = {0.f, 0.f, 0.f, 0.f};
  f32x4 agi[6], agh[6];
#pragma unroll
  for (int j = 0; j < 6; ++j) { agi[j] = zero4; agh[j] = zero4; }

#pragma unroll
  for (int kt = 0; kt < KT_GI; ++kt) {
    short8 a = lds_a(gi_src, gi_S, l15, kt * 32 + lhi * 8);
#pragma unroll
    for (int g = 0; g < 3; ++g) {
#pragma unroll
      for (int tl = 0; tl < 2; ++tl) {
        int nt = g * 16 + wave * 2 + tl;
        short8 b = *(const short8*)(wpack + (size_t)(fbWi + (nt * KT_GI + kt) * 64 + lane) * 8);
        agi[g * 2 + tl] = __builtin_amdgcn_mfma_f32_16x16x32_bf16(a, b, agi[g * 2 + tl], 0, 0, 0);
      }
    }
  }
#pragma unroll
  for (int kt = 0; kt < 8; ++kt) {
    short8 a = lds_a(gh_src, 256, l15, kt * 32 + lhi * 8);
#pragma unroll
    for (int g = 0; g < 3; ++g) {
#pragma unroll
      for (int tl = 0; tl < 2; ++tl) {
        int nt = g * 16 + wave * 2 + tl;
        short8 b = *(const short8*)(wpack + (size_t)(fbWh + (nt * 8 + kt) * 64 + lane) * 8);
        agh[g * 2 + tl] = __builtin_amdgcn_mfma_f32_16x16x32_bf16(a, b, agh[g * 2 + tl], 0, 0, 0);
      }
    }
  }

  __syncthreads();  // all waves done reading h_l(old) before overwrite

#pragma unroll
  for (int tl = 0; tl < 2; ++tl) {
    int c = wave * 32 + tl * 16 + l15;
    float brz = tl ? cb.brz1 : cb.brz0;
    float bzz = tl ? cb.bzz1 : cb.bzz0;
    float bin = tl ? cb.bin1 : cb.bin0;
    float bhn = tl ? cb.bhn1 : cb.bhn0;
#pragma unroll
    for (int j = 0; j < 4; ++j) {
      int row = r0 + j;
      float r = fast_sigmoid(agi[tl][j] + agh[tl][j] + brz);
      float z = fast_sigmoid(agi[2 + tl][j] + agh[2 + tl][j] + bzz);
      float n = fast_tanh(agi[4 + tl][j] + bin + r * (agh[4 + tl][j] + bhn));
      float hold = hf_l[row * 256 + c];
      float hnew = n + z * (hold - n);
      hf_l[row * 256 + c] = hnew;
      hb_l[row * 256 + (c ^ ((row & 7) << 3))] = bf16_rne(hnew);
    }
  }
  __syncthreads();  // h_l(new) visible to next stage
}

__global__ void pack_weights(const float* __restrict__ Wi0, const float* __restrict__ Wh0,
                             const float* __restrict__ Wih12, const float* __restrict__ Whh12,
                             const float* __restrict__ W1, const float* __restrict__ W2,
                             short* __restrict__ outp)
{
  int f = blockIdx.x * blockDim.x + threadIdx.x;
  if (f >= TOTAL_FRAGS) return;
  const float* src; int K; int rel;
  if (f < FB_WH0)        { src = Wi0;            K = 64;  rel = f; }
  else if (f < FB_WI1)   { src = Wh0;            K = 256; rel = f - FB_WH0; }
  else if (f < FB_WH1)   { src = Wih12;          K = 256; rel = f - FB_WI1; }
  else if (f < FB_WI2)   { src = Whh12;          K = 256; rel = f - FB_WH1; }
  else if (f < FB_WH2)   { src = Wih12 + 196608; K = 256; rel = f - FB_WI2; }
  else if (f < FB_W1)    { src = Whh12 + 196608; K = 256; rel = f - FB_WH2; }
  else if (f < FB_W2)    { src = W1;             K = 256; rel = f - FB_W1; }
  else                   { src = W2;             K = 256; rel = f - FB_W2; }
  int lane = rel & 63;
  int q = rel >> 6;
  int KT = K >> 5;
  int kt = q % KT;
  int nt = q / KT;
  int n  = nt * 16 + (lane & 15);
  int k0 = kt * 32 + (lane >> 4) * 8;
  short8 v;
#pragma unroll
  for (int e = 0; e < 8; ++e) v[e] = bf16_rne(src[(size_t)n * K + k0 + e]);
  *(short8*)(outp + (size_t)f * 8) = v;
}

__global__ __launch_bounds__(NTHR, 2)
void timegan_main(const float* __restrict__ noise,
                  const short* __restrict__ wpack,
                  const float* __restrict__ b_ih0, const float* __restrict__ b_hh0,
                  const float* __restrict__ b_ih12, const float* __restrict__ b_hh12,
                  const float* __restrict__ b1v, const float* __restrict__ b2v,
                  float* __restrict__ out)
{
  __shared__ __align__(16) short xbuf[BQ * 64];
  __shared__ __align__(16) short hbuf0[BQ * 256];
  __shared__ __align__(16) short hbuf1[BQ * 256];
  __shared__ __align__(16) short hbuf2[BQ * 256];
  __shared__ __align__(16) short abuf[BQ * 256];
  __shared__ __align__(16) float hf0[BQ * 256];
  __shared__ __align__(16) float hf1[BQ * 256];
  __shared__ __align__(16) float hf2[BQ * 256];

  const int tid = threadIdx.x;
  const int lane = tid & 63, wave = tid >> 6;
  const int l15 = lane & 15, lhi = lane >> 4, r0q = lhi * 4;
  const int brow = blockIdx.x * BQ;

  for (int i = tid; i < BQ * 256; i += NTHR) {
    hbuf0[i] = 0; hbuf1[i] = 0; hbuf2[i] = 0;
    hf0[i] = 0.f; hf1[i] = 0.f; hf2[i] = 0.f;
  }
  for (int i = tid; i < BQ * 64; i += NTHR) {
    int r = i >> 6, c = i & 63;
    xbuf[r * 64 + (c ^ ((r & 7) << 3))] = bf16_rne(noise[(size_t)(brow + r) * 64 + c]);
  }

  CB cb0 = make_cb(b_ih0, b_hh0, wave, l15);
  CB cb1 = make_cb(b_ih12, b_hh12, wave, l15);
  CB cb2 = make_cb(b_ih12 + 768, b_hh12 + 768, wave, l15);
  float bm1_0 = b1v[wave * 32 + l15];
  float bm1_1 = b1v[wave * 32 + 16 + l15];
  float bm2 = (wave < 4) ? b2v[wave * 16 + l15] : 0.f;

  __syncthreads();

  for (int t = 0; t < TT; ++t) {
    gru_cell<2>(xbuf, 64,   hbuf0, wpack, FB_WI0, FB_WH0, hf0, hbuf0, cb0, wave, lane);
    gru_cell<8>(hbuf0, 256, hbuf1, wpack, FB_WI1, FB_WH1, hf1, hbuf1, cb1, wave, lane);
    gru_cell<8>(hbuf1, 256, hbuf2, wpack, FB_WI2, FB_WH2, hf2, hbuf2, cb2, wave, lane);

    // ---- MLP layer 1: a1 = relu(h2 @ W1^T + b1), N=256 (8 waves x 32) ----
    f32x4 zero4 = {0.f, 0.f, 0.f, 0.f};
    f32x4 am[2]; am[0] = zero4; am[1] = zero4;
#pragma unroll
    for (int kt = 0; kt < 8; ++kt) {
      short8 a = lds_a(hbuf2, 256, l15, kt * 32 + lhi * 8);
#pragma unroll
      for (int tl = 0; tl < 2; ++tl) {
        int nt = wave * 2 + tl;
        short8 b = *(const short8*)(wpack + (size_t)(FB_W1 + (nt * 8 + kt) * 64 + lane) * 8);
        am[tl] = __builtin_amdgcn_mfma_f32_16x16x32_bf16(a, b, am[tl], 0, 0, 0);
      }
    }
#pragma unroll
    for (int tl = 0; tl < 2; ++tl) {
      int c = wave * 32 + tl * 16 + l15;
      float bb = tl ? bm1_1 : bm1_0;
#pragma unroll
      for (int j = 0; j < 4; ++j) {
        int row = r0q + j;
        float v = fmaxf(am[tl][j] + bb, 0.f);
        abuf[row * 256 + (c ^ ((row & 7) << 3))] = bf16_rne(v);
      }
    }
    __syncthreads();

    // ---- MLP layer 2: y = tanh(a1 @ W2^T + b2), N=64 (waves 0..3) ----
    if (wave < 4) {
      f32x4 ay = zero4;
#pragma unroll
      for (int kt = 0; kt < 8; ++kt) {
        short8 a = lds_a(abuf, 256, l15, kt * 32 + lhi * 8);
        short8 b = *(const short8*)(wpack + (size_t)(FB_W2 + (wave * 8 + kt) * 64 + lane) * 8);
        ay = __builtin_amdgcn_mfma_f32_16x16x32_bf16(a, b, ay, 0, 0, 0);
      }
      int c = wave * 16 + l15;
#pragma unroll
      for (int j = 0; j < 4; ++j) {
        int row = r0q + j;
        float y = fast_tanh(ay[j] + bm2);
        out[((size_t)(brow + row) * TT + t) * 64 + c] = y;
        xbuf[row * 64 + (c ^ ((row & 7) << 3))] = bf16_rne(y);  // feedback x(t+1)
      }
    }
    __syncthreads();  // x(t+1) visible; end of step
  }
}

extern "C" void kernel_launch(void* const* d_in, const int* in_sizes, int n_in,
                              void* d_out, int out_size, void* d_ws, size_t ws_size,
                              hipStream_t stream)
{
  const float* noise  = (const float*)d_in[0];
  const float* W_ih0  = (const float*)d_in[1];
  const float* W_hh0  = (const float*)d_in[2];
  const float* b_ih0  = (const float*)d_in[3];
  const float* b_hh0  = (const float*)d_in[4];
  const float* W_ih12 = (const float*)d_in[5];
  const float* W_hh12 = (const float*)d_in[6];
  const float* b_ih12 = (const float*)d_in[7];
  const float* b_hh12 = (const float*)d_in[8];
  const float* W1     = (const float*)d_in[9];
  const float* b1     = (const float*)d_in[10];
  const float* W2     = (const float*)d_in[11];
  const float* b2     = (const float*)d_in[12];
  float* out   = (float*)d_out;
  short* wpack = (short*)d_ws;   // 2,228,224 bytes of bf16 packed weights

  pack_weights<<<(TOTAL_FRAGS + 255) / 256, 256, 0, stream>>>(
      W_ih0, W_hh0, W_ih12, W_hh12, W1, W2, wpack);
  timegan_main<<<NBLK, NTHR, 0, stream>>>(
      noise, wpack, b_ih0, b_hh0, b_ih12, b_hh12, b1, b2, out);
}

// Round 2
// 30006.757 us; speedup vs baseline: 1.1453x; 1.1453x over previous
//
#include <hip/hip_runtime.h>
#include <hip/hip_bf16.h>

// TimeGAN generator: 3-layer GRU (H=256) + feedback MLP, B=2048, T=256.
// Round 2: same batch-parallel structure (128 blocks x 16 rows, weights
// streamed from L2 as bf16 frag-packed), but every GEMM is an explicit
// 2-deep software pipeline (issue next 12 B-frag loads while MFMAing the
// previous 12). fp32 h-masters moved from LDS to registers; output stores
// via LDS become full 256B rows.

typedef __attribute__((ext_vector_type(8))) short short8;   // 8 x bf16
typedef __attribute__((ext_vector_type(4))) float f32x4;

#define BQ   16
#define NTHR 512
#define TT   256
#define NBLK 128

// packed-weight fragment bases (in 64-lane-frag units; elements = frag*8)
#define FB_WI0  0        // [768 x  64], KT=2
#define FB_WH0  6144     // [768 x 256], KT=8
#define FB_WI1  30720
#define FB_WH1  55296
#define FB_WI2  79872
#define FB_WH2  104448
#define FB_W1   129024   // [256 x 256]
#define FB_W2   137216   // [ 64 x 256]
#define TOTAL_FRAGS 139264

__device__ __forceinline__ short bf16_rne(float v) {
  union { float f; unsigned u; } c; c.f = v;
  unsigned u = c.u;
  u += 0x7FFFu + ((u >> 16) & 1u);
  return (short)(u >> 16);
}
__device__ __forceinline__ float fast_sigmoid(float x) {
  return 1.0f / (1.0f + __expf(-x));
}
__device__ __forceinline__ float fast_tanh(float x) {
  return 1.0f - 2.0f / (__expf(2.0f * x) + 1.0f);
}

// A-fragment read from a bf16 LDS tile [BQ][S] with XOR swizzle
__device__ __forceinline__ short8 lds_a(const short* buf, int S, int row, int k) {
  int idx = row * S + (k ^ ((row & 7) << 3));
  return *(const short8*)(buf + idx);
}

struct CB { float brz0, brz1, bzz0, bzz1, bin0, bin1, bhn0, bhn1; };

__device__ __forceinline__ CB make_cb(const float* bi, const float* bh, int wave, int l15) {
  CB cb;
  int c0 = wave * 32 + l15, c1 = c0 + 16;
  cb.brz0 = bi[c0] + bh[c0];
  cb.brz1 = bi[c1] + bh[c1];
  cb.bzz0 = bi[256 + c0] + bh[256 + c0];
  cb.bzz1 = bi[256 + c1] + bh[256 + c1];
  cb.bin0 = bi[512 + c0];
  cb.bin1 = bi[512 + c1];
  cb.bhn0 = bh[512 + c0];
  cb.bhn1 = bh[512 + c1];
  return cb;
}

// B-frag pointer: frag index (fb + (nt*KT+kt)*64 + lane), 8 shorts each
#define B_ADDR(fb, nt, kt, KT) \
  ((const short8*)(wpack + ((size_t)(fb) + (size_t)((nt) * (KT) + (kt)) * 64 + lane) * 8))

// Load one chunk (2 kt-slices x 6 nt-frags) of gate weights into buf[12]
#define LOAD6(buf, fb, KT, c) do {                                        \
  _Pragma("unroll") for (int f_ = 0; f_ < 6; ++f_) {                      \
    int nt_ = (f_ >> 1) * 16 + wave * 2 + (f_ & 1);                       \
    buf[f_]     = *B_ADDR(fb, nt_, (c) * 2,     KT);                      \
    buf[6 + f_] = *B_ADDR(fb, nt_, (c) * 2 + 1, KT);                      \
  } } while (0)

// MFMA one chunk: 2 LDS A-reads + 12 MFMAs into acc[6]
#define MFMA6(buf, acc, asrc, S, c) do {                                  \
  short8 a0_ = lds_a(asrc, S, l15, ((c) * 2)     * 32 + lhi * 8);         \
  short8 a1_ = lds_a(asrc, S, l15, ((c) * 2 + 1) * 32 + lhi * 8);         \
  _Pragma("unroll") for (int f_ = 0; f_ < 6; ++f_) {                      \
    acc[f_] = __builtin_amdgcn_mfma_f32_16x16x32_bf16(a0_, buf[f_],     acc[f_], 0, 0, 0); \
    acc[f_] = __builtin_amdgcn_mfma_f32_16x16x32_bf16(a1_, buf[6 + f_], acc[f_], 0, 0, 0); \
  } } while (0)

// One GRU cell, 2-deep pipelined. KTGI = K-tiles of the gi GEMM (2 or 8).
template<int KTGI>
__device__ __forceinline__ void cell(
    const short* gi_src, int gi_S, const short* gh_src,
    const short* __restrict__ wpack, int fbWi, int fbWh,
    float (&hm)[8], short* hb_l, const CB& cb,
    int wave, int lane, int l15, int lhi, int r0q)
{
  short8 bufA[12], bufB[12];
  f32x4 z4 = {0.f, 0.f, 0.f, 0.f};
  f32x4 agi[6], agh[6];
#pragma unroll
  for (int j = 0; j < 6; ++j) { agi[j] = z4; agh[j] = z4; }

  if constexpr (KTGI == 8) {
    LOAD6(bufA, fbWi, 8, 0);
    LOAD6(bufB, fbWi, 8, 1); MFMA6(bufA, agi, gi_src, gi_S, 0);
    LOAD6(bufA, fbWi, 8, 2); MFMA6(bufB, agi, gi_src, gi_S, 1);
    LOAD6(bufB, fbWi, 8, 3); MFMA6(bufA, agi, gi_src, gi_S, 2);
    LOAD6(bufA, fbWh, 8, 0); MFMA6(bufB, agi, gi_src, gi_S, 3);
    LOAD6(bufB, fbWh, 8, 1); MFMA6(bufA, agh, gh_src, 256, 0);
    LOAD6(bufA, fbWh, 8, 2); MFMA6(bufB, agh, gh_src, 256, 1);
    LOAD6(bufB, fbWh, 8, 3); MFMA6(bufA, agh, gh_src, 256, 2);
                             MFMA6(bufB, agh, gh_src, 256, 3);
  } else {
    LOAD6(bufA, fbWi, 2, 0);
    LOAD6(bufB, fbWh, 8, 0); MFMA6(bufA, agi, gi_src, gi_S, 0);
    LOAD6(bufA, fbWh, 8, 1); MFMA6(bufB, agh, gh_src, 256, 0);
    LOAD6(bufB, fbWh, 8, 2); MFMA6(bufA, agh, gh_src, 256, 1);
    LOAD6(bufA, fbWh, 8, 3); MFMA6(bufB, agh, gh_src, 256, 2);
                             MFMA6(bufA, agh, gh_src, 256, 3);
  }

  __syncthreads();  // all waves done reading gh_src before overwrite

#pragma unroll
  for (int tl = 0; tl < 2; ++tl) {
    int c = wave * 32 + tl * 16 + l15;
    float brz = tl ? cb.brz1 : cb.brz0;
    float bzz = tl ? cb.bzz1 : cb.bzz0;
    float bin = tl ? cb.bin1 : cb.bin0;
    float bhn = tl ? cb.bhn1 : cb.bhn0;
#pragma unroll
    for (int j = 0; j < 4; ++j) {
      int row = r0q + j;
      float r = fast_sigmoid(agi[tl][j] + agh[tl][j] + brz);
      float z = fast_sigmoid(agi[2 + tl][j] + agh[2 + tl][j] + bzz);
      float n = fast_tanh(agi[4 + tl][j] + bin + r * (agh[4 + tl][j] + bhn));
      float hold = hm[tl * 4 + j];
      float hnew = n + z * (hold - n);
      hm[tl * 4 + j] = hnew;
      hb_l[row * 256 + (c ^ ((row & 7) << 3))] = bf16_rne(hnew);
    }
  }
  __syncthreads();  // h_l(new) visible to next stage
}

__global__ void pack_weights(const float* __restrict__ Wi0, const float* __restrict__ Wh0,
                             const float* __restrict__ Wih12, const float* __restrict__ Whh12,
                             const float* __restrict__ W1, const float* __restrict__ W2,
                             short* __restrict__ outp)
{
  int f = blockIdx.x * blockDim.x + threadIdx.x;
  if (f >= TOTAL_FRAGS) return;
  const float* src; int K; int rel;
  if (f < FB_WH0)        { src = Wi0;            K = 64;  rel = f; }
  else if (f < FB_WI1)   { src = Wh0;            K = 256; rel = f - FB_WH0; }
  else if (f < FB_WH1)   { src = Wih12;          K = 256; rel = f - FB_WI1; }
  else if (f < FB_WI2)   { src = Whh12;          K = 256; rel = f - FB_WH1; }
  else if (f < FB_WH2)   { src = Wih12 + 196608; K = 256; rel = f - FB_WI2; }
  else if (f < FB_W1)    { src = Whh12 + 196608; K = 256; rel = f - FB_WH2; }
  else if (f < FB_W2)    { src = W1;             K = 256; rel = f - FB_W1; }
  else                   { src = W2;             K = 256; rel = f - FB_W2; }
  int lane = rel & 63;
  int q = rel >> 6;
  int KT = K >> 5;
  int kt = q % KT;
  int nt = q / KT;
  int n  = nt * 16 + (lane & 15);
  int k0 = kt * 32 + (lane >> 4) * 8;
  short8 v;
#pragma unroll
  for (int e = 0; e < 8; ++e) v[e] = bf16_rne(src[(size_t)n * K + k0 + e]);
  *(short8*)(outp + (size_t)f * 8) = v;
}

__global__ __launch_bounds__(NTHR, 2)
void timegan_main(const float* __restrict__ noise,
                  const short* __restrict__ wpack,
                  const float* __restrict__ b_ih0, const float* __restrict__ b_hh0,
                  const float* __restrict__ b_ih12, const float* __restrict__ b_hh12,
                  const float* __restrict__ b1v, const float* __restrict__ b2v,
                  float* __restrict__ out)
{
  __shared__ __align__(16) short xbuf[BQ * 64];
  __shared__ __align__(16) short hbuf0[BQ * 256];
  __shared__ __align__(16) short hbuf1[BQ * 256];
  __shared__ __align__(16) short hbuf2[BQ * 256];
  __shared__ __align__(16) short abuf[BQ * 256];
  __shared__ __align__(16) float ybuf[BQ * 64];

  const int tid = threadIdx.x;
  const int lane = tid & 63, wave = tid >> 6;
  const int l15 = lane & 15, lhi = lane >> 4, r0q = lhi * 4;
  const int brow = blockIdx.x * BQ;

  float hm0[8], hm1[8], hm2[8];
#pragma unroll
  for (int j = 0; j < 8; ++j) { hm0[j] = 0.f; hm1[j] = 0.f; hm2[j] = 0.f; }

  for (int i = tid; i < BQ * 256; i += NTHR) {
    hbuf0[i] = 0; hbuf1[i] = 0; hbuf2[i] = 0;
  }
  for (int i = tid; i < BQ * 64; i += NTHR) {
    int r = i >> 6, c = i & 63;
    xbuf[r * 64 + (c ^ ((r & 7) << 3))] = bf16_rne(noise[(size_t)(brow + r) * 64 + c]);
  }

  CB cb0 = make_cb(b_ih0, b_hh0, wave, l15);
  CB cb1 = make_cb(b_ih12, b_hh12, wave, l15);
  CB cb2 = make_cb(b_ih12 + 768, b_hh12 + 768, wave, l15);
  float bm1_0 = b1v[wave * 32 + l15];
  float bm1_1 = b1v[wave * 32 + 16 + l15];
  float bm2 = (wave < 4) ? b2v[wave * 16 + l15] : 0.f;

  __syncthreads();

  for (int t = 0; t < TT; ++t) {
    cell<2>(xbuf, 64,   hbuf0, wpack, FB_WI0, FB_WH0, hm0, hbuf0, cb0,
            wave, lane, l15, lhi, r0q);
    cell<8>(hbuf0, 256, hbuf1, wpack, FB_WI1, FB_WH1, hm1, hbuf1, cb1,
            wave, lane, l15, lhi, r0q);
    cell<8>(hbuf1, 256, hbuf2, wpack, FB_WI2, FB_WH2, hm2, hbuf2, cb2,
            wave, lane, l15, lhi, r0q);

    // ---- MLP layer 1: a1 = relu(h2 @ W1^T + b1), N=256, pipelined ----
    f32x4 z4 = {0.f, 0.f, 0.f, 0.f};
    f32x4 am[2]; am[0] = z4; am[1] = z4;
    short8 m1A[4], m1B[4];

#define LOADM1(buf, c) do {                                               \
    _Pragma("unroll") for (int f_ = 0; f_ < 2; ++f_) {                    \
      int nt_ = wave * 2 + f_;                                            \
      buf[f_]     = *B_ADDR(FB_W1, nt_, (c) * 2,     8);                  \
      buf[2 + f_] = *B_ADDR(FB_W1, nt_, (c) * 2 + 1, 8);                  \
    } } while (0)
#define MFMAM1(buf, c) do {                                               \
    short8 a0_ = lds_a(hbuf2, 256, l15, ((c) * 2)     * 32 + lhi * 8);    \
    short8 a1_ = lds_a(hbuf2, 256, l15, ((c) * 2 + 1) * 32 + lhi * 8);    \
    _Pragma("unroll") for (int f_ = 0; f_ < 2; ++f_) {                    \
      am[f_] = __builtin_amdgcn_mfma_f32_16x16x32_bf16(a0_, buf[f_],     am[f_], 0, 0, 0); \
      am[f_] = __builtin_amdgcn_mfma_f32_16x16x32_bf16(a1_, buf[2 + f_], am[f_], 0, 0, 0); \
    } } while (0)

    LOADM1(m1A, 0);
    LOADM1(m1B, 1); MFMAM1(m1A, 0);
    LOADM1(m1A, 2); MFMAM1(m1B, 1);
    LOADM1(m1B, 3); MFMAM1(m1A, 2);
    // prefetch MLP2 weights (waves 0-3) while finishing MLP1
    short8 m2[8];
    if (wave < 4) {
#pragma unroll
      for (int kt = 0; kt < 8; ++kt) m2[kt] = *B_ADDR(FB_W2, wave, kt, 8);
    }
    MFMAM1(m1B, 3);

#pragma unroll
    for (int tl = 0; tl < 2; ++tl) {
      int c = wave * 32 + tl * 16 + l15;
      float bb = tl ? bm1_1 : bm1_0;
#pragma unroll
      for (int j = 0; j < 4; ++j) {
        int row = r0q + j;
        float v = fmaxf(am[tl][j] + bb, 0.f);
        abuf[row * 256 + (c ^ ((row & 7) << 3))] = bf16_rne(v);
      }
    }
    __syncthreads();

    // ---- MLP layer 2: y = tanh(a1 @ W2^T + b2), N=64 (waves 0..3) ----
    if (wave < 4) {
      f32x4 ay = z4;
#pragma unroll
      for (int kt = 0; kt < 8; ++kt) {
        short8 a = lds_a(abuf, 256, l15, kt * 32 + lhi * 8);
        ay = __builtin_amdgcn_mfma_f32_16x16x32_bf16(a, m2[kt], ay, 0, 0, 0);
      }
      int c = wave * 16 + l15;
#pragma unroll
      for (int j = 0; j < 4; ++j) {
        int row = r0q + j;
        float y = fast_tanh(ay[j] + bm2);
        ybuf[row * 64 + c] = y;
        xbuf[row * 64 + (c ^ ((row & 7) << 3))] = bf16_rne(y);  // feedback
      }
    }
    __syncthreads();

    // ---- store out: wave w stores rows 2w, 2w+1 as full 256B rows ----
    {
      int r0 = wave * 2;
      size_t base = ((size_t)(brow + r0) * TT + t) * 64;
      out[base + lane] = ybuf[r0 * 64 + lane];
      out[base + (size_t)TT * 64 + lane] = ybuf[(r0 + 1) * 64 + lane];
    }
    // next step's ybuf/xbuf writes are ordered behind the barriers inside
    // cell<2>, so no extra barrier needed here.
  }
}

extern "C" void kernel_launch(void* const* d_in, const int* in_sizes, int n_in,
                              void* d_out, int out_size, void* d_ws, size_t ws_size,
                              hipStream_t stream)
{
  const float* noise  = (const float*)d_in[0];
  const float* W_ih0  = (const float*)d_in[1];
  const float* W_hh0  = (const float*)d_in[2];
  const float* b_ih0  = (const float*)d_in[3];
  const float* b_hh0  = (const float*)d_in[4];
  const float* W_ih12 = (const float*)d_in[5];
  const float* W_hh12 = (const float*)d_in[6];
  const float* b_ih12 = (const float*)d_in[7];
  const float* b_hh12 = (const float*)d_in[8];
  const float* W1     = (const float*)d_in[9];
  const float* b1     = (const float*)d_in[10];
  const float* W2     = (const float*)d_in[11];
  const float* b2     = (const float*)d_in[12];
  float* out   = (float*)d_out;
  short* wpack = (short*)d_ws;   // 2,228,224 bytes of bf16 packed weights

  pack_weights<<<(TOTAL_FRAGS + 255) / 256, 256, 0, stream>>>(
      W_ih0, W_hh0, W_ih12, W_hh12, W1, W2, wpack);
  timegan_main<<<NBLK, NTHR, 0, stream>>>(
      noise, wpack, b_ih0, b_hh0, b_ih12, b_hh12, b1, b2, out);
}

// Round 3
// 29031.482 us; speedup vs baseline: 1.1838x; 1.0336x over previous
//
#include <hip/hip_runtime.h>
#include <hip/hip_bf16.h>

// TimeGAN generator: 3-layer GRU (H=256) + feedback MLP, B=2048, T=256.
// Round 3: weight streaming via global_load_lds into per-wave-private LDS
// ring buffers with inline-asm counted vmcnt (never drained to 0) and raw
// s_barrier (lgkmcnt-only) so weight prefetch stays in flight across all
// barriers. MLP1/MLP2 weights persistent in registers. 128 blocks x 16 rows.

typedef __attribute__((ext_vector_type(8))) short short8;   // 8 x bf16
typedef __attribute__((ext_vector_type(4))) float f32x4;

#define BQ   16
#define NTHR 512
#define TT   256
#define NBLK 128
#define SL_PER_STEP 42   // streamed slices per step (6 frags x 1KB each)

// packed-weight fragment bases (in 64-lane-frag units; elements = frag*8)
#define FB_WI0  0        // [768 x  64], KT=2
#define FB_WH0  6144     // [768 x 256], KT=8
#define FB_WI1  30720
#define FB_WH1  55296
#define FB_WI2  79872
#define FB_WH2  104448
#define FB_W1   129024   // [256 x 256]
#define FB_W2   137216   // [ 64 x 256]
#define TOTAL_FRAGS 139264

__device__ __forceinline__ short bf16_rne(float v) {
  union { float f; unsigned u; } c; c.f = v;
  unsigned u = c.u;
  u += 0x7FFFu + ((u >> 16) & 1u);
  return (short)(u >> 16);
}
__device__ __forceinline__ float fast_sigmoid(float x) {
  return 1.0f / (1.0f + __expf(-x));
}
__device__ __forceinline__ float fast_tanh(float x) {
  return 1.0f - 2.0f / (__expf(2.0f * x) + 1.0f);
}

// A-fragment read from a bf16 LDS tile [BQ][S] with XOR swizzle
__device__ __forceinline__ short8 lds_a(const short* buf, int S, int row, int k) {
  int idx = row * S + (k ^ ((row & 7) << 3));
  return *(const short8*)(buf + idx);
}

struct CB { float brz0, brz1, bzz0, bzz1, bin0, bin1, bhn0, bhn1; };

__device__ __forceinline__ CB make_cb(const float* bi, const float* bh, int wave, int l15) {
  CB cb;
  int c0 = wave * 32 + l15, c1 = c0 + 16;
  cb.brz0 = bi[c0] + bh[c0];
  cb.brz1 = bi[c1] + bh[c1];
  cb.bzz0 = bi[256 + c0] + bh[256 + c0];
  cb.bzz1 = bi[256 + c1] + bh[256 + c1];
  cb.bin0 = bi[512 + c0];
  cb.bin1 = bi[512 + c1];
  cb.bhn0 = bh[512 + c0];
  cb.bhn1 = bh[512 + c1];
  return cb;
}

#define B_ADDR(fb, nt, kt, KT) \
  ((const short8*)(wpack + ((size_t)(fb) + (size_t)((nt) * (KT) + (kt)) * 64 + lane) * 8))

// raw barrier: drains LDS ops only; weight-load vmcnt stays outstanding
__device__ __forceinline__ void block_sync_lds() {
  asm volatile("s_waitcnt lgkmcnt(0)" ::: "memory");
  __builtin_amdgcn_sched_barrier(0);
  __builtin_amdgcn_s_barrier();
  __builtin_amdgcn_sched_barrier(0);
}

// Issue one stream slice: 6 global_load_lds_dwordx4 (1 KB each) into this
// wave's private ring buffer. Slice schedule (per step, 42 slices):
//  0..1  cell0 gi (FB_WI0, KT=2)    2..9  cell0 gh (FB_WH0, KT=8)
// 10..17 cell1 gi (FB_WI1)         18..25 cell1 gh (FB_WH1)
// 26..33 cell2 gi (FB_WI2)         34..41 cell2 gh (FB_WH2)
__device__ __forceinline__ void issue_slice(const short* __restrict__ wpack,
                                            int sl, int wave, int lane, short* wr) {
  int fb, KT, kt;
  if (sl < 2)       { fb = FB_WI0; KT = 2; kt = sl; }
  else if (sl < 10) { fb = FB_WH0; KT = 8; kt = sl - 2; }
  else if (sl < 18) { fb = FB_WI1; KT = 8; kt = sl - 10; }
  else if (sl < 26) { fb = FB_WH1; KT = 8; kt = sl - 18; }
  else if (sl < 34) { fb = FB_WI2; KT = 8; kt = sl - 26; }
  else              { fb = FB_WH2; KT = 8; kt = sl - 34; }
  __builtin_amdgcn_sched_barrier(0);
#pragma unroll
  for (int f = 0; f < 6; ++f) {
    int nt = (f >> 1) * 16 + wave * 2 + (f & 1);
    const short* g = wpack + ((size_t)fb + (size_t)(nt * KT + kt) * 64 + lane) * 8;
    __builtin_amdgcn_global_load_lds(
        (const __attribute__((address_space(1))) void*)g,
        (__attribute__((address_space(3))) void*)(wr + f * 512), 16, 0, 0);
  }
  __builtin_amdgcn_sched_barrier(0);
}

// Consume one resident slice: wait vmcnt(6) (slice landed; next slice + any
// stores may stay in flight), 1 A-read + 6 MFMAs, then drain lgkm so the
// buffer can be re-targeted by the next issue.
__device__ __forceinline__ void compute_slice(const short* wr, f32x4 (&acc)[6],
                                              const short* asrc, int S, int kt,
                                              int l15, int lhi, int lane) {
  asm volatile("s_waitcnt vmcnt(6)" ::: "memory");
  __builtin_amdgcn_sched_barrier(0);
  short8 a = lds_a(asrc, S, l15, kt * 32 + lhi * 8);
  const short* bp = wr + lane * 8;
#pragma unroll
  for (int f = 0; f < 6; ++f)
    acc[f] = __builtin_amdgcn_mfma_f32_16x16x32_bf16(
        a, *(const short8*)(bp + f * 512), acc[f], 0, 0, 0);
  asm volatile("s_waitcnt lgkmcnt(0)" ::: "memory");
  __builtin_amdgcn_sched_barrier(0);
}

// One GRU cell with streamed weights. SB = first slice of this cell.
template<int SB, int NSL, int KTGI>
__device__ __forceinline__ void cell_stream(
    const short* gi_src, int gi_S, const short* gh_src,
    const short* __restrict__ wpack, short (*wr2)[3072],
    float (&hm)[8], short* hb_l, const CB& cb,
    int wave, int lane, int l15, int lhi, int r0q)
{
  f32x4 z4 = {0.f, 0.f, 0.f, 0.f};
  f32x4 agi[6], agh[6];
#pragma unroll
  for (int j = 0; j < 6; ++j) { agi[j] = z4; agh[j] = z4; }

#pragma unroll
  for (int s = 0; s < NSL; ++s) {
    const short* wr = wr2[(SB + s) & 1];
    if (s < KTGI)
      compute_slice(wr, agi, gi_src, gi_S, s, l15, lhi, lane);
    else
      compute_slice(wr, agh, gh_src, 256, s - KTGI, l15, lhi, lane);
    const int nsl = (SB + s + 2) % SL_PER_STEP;
    issue_slice(wpack, nsl, wave, lane, wr2[nsl & 1]);
  }

  block_sync_lds();  // all waves done reading old h before overwrite

#pragma unroll
  for (int tl = 0; tl < 2; ++tl) {
    int c = wave * 32 + tl * 16 + l15;
    float brz = tl ? cb.brz1 : cb.brz0;
    float bzz = tl ? cb.bzz1 : cb.bzz0;
    float bin = tl ? cb.bin1 : cb.bin0;
    float bhn = tl ? cb.bhn1 : cb.bhn0;
#pragma unroll
    for (int j = 0; j < 4; ++j) {
      int row = r0q + j;
      float r = fast_sigmoid(agi[tl][j] + agh[tl][j] + brz);
      float z = fast_sigmoid(agi[2 + tl][j] + agh[2 + tl][j] + bzz);
      float n = fast_tanh(agi[4 + tl][j] + bin + r * (agh[4 + tl][j] + bhn));
      float hold = hm[tl * 4 + j];
      float hnew = n + z * (hold - n);
      hm[tl * 4 + j] = hnew;
      hb_l[row * 256 + (c ^ ((row & 7) << 3))] = bf16_rne(hnew);
    }
  }
  block_sync_lds();  // h(new) visible to next stage
}

__global__ void pack_weights(const float* __restrict__ Wi0, const float* __restrict__ Wh0,
                             const float* __restrict__ Wih12, const float* __restrict__ Whh12,
                             const float* __restrict__ W1, const float* __restrict__ W2,
                             short* __restrict__ outp)
{
  int f = blockIdx.x * blockDim.x + threadIdx.x;
  if (f >= TOTAL_FRAGS) return;
  const float* src; int K; int rel;
  if (f < FB_WH0)        { src = Wi0;            K = 64;  rel = f; }
  else if (f < FB_WI1)   { src = Wh0;            K = 256; rel = f - FB_WH0; }
  else if (f < FB_WH1)   { src = Wih12;          K = 256; rel = f - FB_WI1; }
  else if (f < FB_WI2)   { src = Whh12;          K = 256; rel = f - FB_WH1; }
  else if (f < FB_WH2)   { src = Wih12 + 196608; K = 256; rel = f - FB_WI2; }
  else if (f < FB_W1)    { src = Whh12 + 196608; K = 256; rel = f - FB_WH2; }
  else if (f < FB_W2)    { src = W1;             K = 256; rel = f - FB_W1; }
  else                   { src = W2;             K = 256; rel = f - FB_W2; }
  int lane = rel & 63;
  int q = rel >> 6;
  int KT = K >> 5;
  int kt = q % KT;
  int nt = q / KT;
  int n  = nt * 16 + (lane & 15);
  int k0 = kt * 32 + (lane >> 4) * 8;
  short8 v;
#pragma unroll
  for (int e = 0; e < 8; ++e) v[e] = bf16_rne(src[(size_t)n * K + k0 + e]);
  *(short8*)(outp + (size_t)f * 8) = v;
}

__global__ __launch_bounds__(NTHR, 2)
void timegan_main(const float* __restrict__ noise,
                  const short* __restrict__ wpack,
                  const float* __restrict__ b_ih0, const float* __restrict__ b_hh0,
                  const float* __restrict__ b_ih12, const float* __restrict__ b_hh12,
                  const float* __restrict__ b1v, const float* __restrict__ b2v,
                  float* __restrict__ out)
{
  __shared__ __align__(16) short wring[8][2][3072];   // 96 KB weight ring
  __shared__ __align__(16) short xbuf[BQ * 64];
  __shared__ __align__(16) short hbuf0[BQ * 256];
  __shared__ __align__(16) short hbuf1[BQ * 256];
  __shared__ __align__(16) short hbuf2[BQ * 256];
  __shared__ __align__(16) short abuf[BQ * 256];
  __shared__ __align__(16) float ybuf[BQ * 64];

  const int tid = threadIdx.x;
  const int lane = tid & 63, wave = tid >> 6;
  const int l15 = lane & 15, lhi = lane >> 4, r0q = lhi * 4;
  const int brow = blockIdx.x * BQ;

  float hm0[8], hm1[8], hm2[8];
#pragma unroll
  for (int j = 0; j < 8; ++j) { hm0[j] = 0.f; hm1[j] = 0.f; hm2[j] = 0.f; }

  for (int i = tid; i < BQ * 256; i += NTHR) {
    hbuf0[i] = 0; hbuf1[i] = 0; hbuf2[i] = 0;
  }
  for (int i = tid; i < BQ * 64; i += NTHR) {
    int r = i >> 6, c = i & 63;
    xbuf[r * 64 + (c ^ ((r & 7) << 3))] = bf16_rne(noise[(size_t)(brow + r) * 64 + c]);
  }

  CB cb0 = make_cb(b_ih0, b_hh0, wave, l15);
  CB cb1 = make_cb(b_ih12, b_hh12, wave, l15);
  CB cb2 = make_cb(b_ih12 + 768, b_hh12 + 768, wave, l15);
  float bm1_0 = b1v[wave * 32 + l15];
  float bm1_1 = b1v[wave * 32 + 16 + l15];
  float bm2 = (wave < 4) ? b2v[wave * 16 + l15] : 0.f;

  // persistent register weights: MLP1 (16 frags) + MLP2 (8 frags, waves 0-3)
  short8 m1[16];
#pragma unroll
  for (int kt = 0; kt < 8; ++kt) {
    m1[kt * 2]     = *B_ADDR(FB_W1, wave * 2,     kt, 8);
    m1[kt * 2 + 1] = *B_ADDR(FB_W1, wave * 2 + 1, kt, 8);
  }
  short8 m2[8];
  if (wave < 4) {
#pragma unroll
    for (int kt = 0; kt < 8; ++kt) m2[kt] = *B_ADDR(FB_W2, wave, kt, 8);
  }

  // drain all init-time vmem so the counted-vmcnt stream starts clean
  asm volatile("s_waitcnt vmcnt(0)" ::: "memory");
  __builtin_amdgcn_sched_barrier(0);
  block_sync_lds();

  // prologue: 2 slices in flight
  issue_slice(wpack, 0, wave, lane, wring[wave][0]);
  issue_slice(wpack, 1, wave, lane, wring[wave][1]);

#pragma unroll 1
  for (int t = 0; t < TT; ++t) {
    cell_stream<0, 10, 2>(xbuf, 64,   hbuf0, wpack, wring[wave], hm0, hbuf0, cb0,
                          wave, lane, l15, lhi, r0q);
    cell_stream<10, 16, 8>(hbuf0, 256, hbuf1, wpack, wring[wave], hm1, hbuf1, cb1,
                           wave, lane, l15, lhi, r0q);
    cell_stream<26, 16, 8>(hbuf1, 256, hbuf2, wpack, wring[wave], hm2, hbuf2, cb2,
                           wave, lane, l15, lhi, r0q);

    // ---- MLP1: a1 = relu(h2 @ W1^T + b1), weights in registers ----
    f32x4 z4 = {0.f, 0.f, 0.f, 0.f};
    f32x4 am[2]; am[0] = z4; am[1] = z4;
#pragma unroll
    for (int kt = 0; kt < 8; ++kt) {
      short8 a = lds_a(hbuf2, 256, l15, kt * 32 + lhi * 8);
      am[0] = __builtin_amdgcn_mfma_f32_16x16x32_bf16(a, m1[kt * 2],     am[0], 0, 0, 0);
      am[1] = __builtin_amdgcn_mfma_f32_16x16x32_bf16(a, m1[kt * 2 + 1], am[1], 0, 0, 0);
    }
#pragma unroll
    for (int tl = 0; tl < 2; ++tl) {
      int c = wave * 32 + tl * 16 + l15;
      float bb = tl ? bm1_1 : bm1_0;
#pragma unroll
      for (int j = 0; j < 4; ++j) {
        int row = r0q + j;
        float v = fmaxf(am[tl][j] + bb, 0.f);
        abuf[row * 256 + (c ^ ((row & 7) << 3))] = bf16_rne(v);
      }
    }
    block_sync_lds();

    // ---- MLP2: y = tanh(a1 @ W2^T + b2), weights in registers ----
    if (wave < 4) {
      f32x4 ay = z4;
#pragma unroll
      for (int kt = 0; kt < 8; ++kt) {
        short8 a = lds_a(abuf, 256, l15, kt * 32 + lhi * 8);
        ay = __builtin_amdgcn_mfma_f32_16x16x32_bf16(a, m2[kt], ay, 0, 0, 0);
      }
      int c = wave * 16 + l15;
#pragma unroll
      for (int j = 0; j < 4; ++j) {
        int row = r0q + j;
        float y = fast_tanh(ay[j] + bm2);
        ybuf[row * 64 + c] = y;
        xbuf[row * 64 + (c ^ ((row & 7) << 3))] = bf16_rne(y);  // feedback
      }
    }
    block_sync_lds();

    // ---- store y(t): wave w stores rows 2w, 2w+1 as full 256B rows ----
    {
      int r0 = wave * 2;
      size_t base = ((size_t)(brow + r0) * TT + t) * 64;
      out[base + lane] = ybuf[r0 * 64 + lane];
      out[base + (size_t)TT * 64 + lane] = ybuf[(r0 + 1) * 64 + lane];
    }
  }

  // drain the over-issued prefetch (slices for step TT) before wave exit:
  // in-flight global_load_lds writes must not land in reallocated LDS.
  asm volatile("s_waitcnt vmcnt(0)" ::: "memory");
}

extern "C" void kernel_launch(void* const* d_in, const int* in_sizes, int n_in,
                              void* d_out, int out_size, void* d_ws, size_t ws_size,
                              hipStream_t stream)
{
  const float* noise  = (const float*)d_in[0];
  const float* W_ih0  = (const float*)d_in[1];
  const float* W_hh0  = (const float*)d_in[2];
  const float* b_ih0  = (const float*)d_in[3];
  const float* b_hh0  = (const float*)d_in[4];
  const float* W_ih12 = (const float*)d_in[5];
  const float* W_hh12 = (const float*)d_in[6];
  const float* b_ih12 = (const float*)d_in[7];
  const float* b_hh12 = (const float*)d_in[8];
  const float* W1     = (const float*)d_in[9];
  const float* b1     = (const float*)d_in[10];
  const float* W2     = (const float*)d_in[11];
  const float* b2     = (const float*)d_in[12];
  float* out   = (float*)d_out;
  short* wpack = (short*)d_ws;   // 2,228,224 bytes of bf16 packed weights

  pack_weights<<<(TOTAL_FRAGS + 255) / 256, 256, 0, stream>>>(
      W_ih0, W_hh0, W_ih12, W_hh12, W1, W2, wpack);
  timegan_main<<<NBLK, NTHR, 0, stream>>>(
      noise, wpack, b_ih0, b_hh0, b_ih12, b_hh12, b1, b2, out);
}

// Round 4
// 23715.883 us; speedup vs baseline: 1.4491x; 1.2241x over previous
//
#include <hip/hip_runtime.h>
#include <hip/hip_bf16.h>

// TimeGAN generator: 3-layer GRU (H=256) + feedback MLP, B=2048, T=256.
// Round 4: de-hotspot the L2 by per-block K-rotation (each block consumes &
// prefetches kt-slices in a rotated order -> concurrent blocks touch disjoint
// lines), plus deeper prefetch: 3KB sub-slices, 4-deep LDS ring per wave,
// issue s+3 / wait vmcnt(9) -> 9KB/wave in flight.

typedef __attribute__((ext_vector_type(8))) short short8;   // 8 x bf16
typedef __attribute__((ext_vector_type(4))) float f32x4;

#define BQ   16
#define NTHR 512
#define TT   256
#define NBLK 128
#define NSUB 84     // sub-slices per step (3 frags = 3KB each, per wave)

// packed-weight fragment bases (in 64-lane-frag units; elements = frag*8)
#define FB_WI0  0        // [768 x  64], KT=2
#define FB_WH0  6144     // [768 x 256], KT=8
#define FB_WI1  30720
#define FB_WH1  55296
#define FB_WI2  79872
#define FB_WH2  104448
#define FB_W1   129024   // [256 x 256]
#define FB_W2   137216   // [ 64 x 256]
#define TOTAL_FRAGS 139264

__device__ __forceinline__ short bf16_rne(float v) {
  union { float f; unsigned u; } c; c.f = v;
  unsigned u = c.u;
  u += 0x7FFFu + ((u >> 16) & 1u);
  return (short)(u >> 16);
}
__device__ __forceinline__ float fast_sigmoid(float x) {
  return 1.0f / (1.0f + __expf(-x));
}
__device__ __forceinline__ float fast_tanh(float x) {
  return 1.0f - 2.0f / (__expf(2.0f * x) + 1.0f);
}

// A-fragment read from a bf16 LDS tile [BQ][S] with XOR swizzle
__device__ __forceinline__ short8 lds_a(const short* buf, int S, int row, int k) {
  int idx = row * S + (k ^ ((row & 7) << 3));
  return *(const short8*)(buf + idx);
}

struct CB { float brz0, brz1, bzz0, bzz1, bin0, bin1, bhn0, bhn1; };

__device__ __forceinline__ CB make_cb(const float* bi, const float* bh, int wave, int l15) {
  CB cb;
  int c0 = wave * 32 + l15, c1 = c0 + 16;
  cb.brz0 = bi[c0] + bh[c0];
  cb.brz1 = bi[c1] + bh[c1];
  cb.bzz0 = bi[256 + c0] + bh[256 + c0];
  cb.bzz1 = bi[256 + c1] + bh[256 + c1];
  cb.bin0 = bi[512 + c0];
  cb.bin1 = bi[512 + c1];
  cb.bhn0 = bh[512 + c0];
  cb.bhn1 = bh[512 + c1];
  return cb;
}

#define B_ADDR(fb, nt, kt, KT) \
  ((const short8*)(wpack + ((size_t)(fb) + (size_t)((nt) * (KT) + (kt)) * 64 + lane) * 8))

// raw barrier: drains LDS ops only; weight-load vmcnt stays outstanding
__device__ __forceinline__ void block_sync_lds() {
  asm volatile("s_waitcnt lgkmcnt(0)" ::: "memory");
  __builtin_amdgcn_sched_barrier(0);
  __builtin_amdgcn_s_barrier();
  __builtin_amdgcn_sched_barrier(0);
}

// Issue one 3KB sub-slice (3 x global_load_lds_dwordx4). Sub-slice map per
// step (84 subs): cell0 gi 0..3 (KT=2), gh 4..19; cell1 gi 20..35, gh 36..51;
// cell2 gi 52..67, gh 68..83. Each kt = 2 subs (h=0: frags 0-2, h=1: 3-5).
// Per-block rotation r2/r8 spreads concurrent blocks across kt-slices.
__device__ __forceinline__ void issue_sub(const short* __restrict__ wpack,
                                          int s, int r2, int r8,
                                          int wave, int lane, short* ringbuf) {
  s = s % NSUB;   // compile-time folded (s is a constant at each call site)
  int fb, KT, rot, u;
  if (s < 4)       { fb = FB_WI0; KT = 2; u = s;      rot = r2; }
  else if (s < 20) { fb = FB_WH0; KT = 8; u = s - 4;  rot = r8; }
  else if (s < 36) { fb = FB_WI1; KT = 8; u = s - 20; rot = r8; }
  else if (s < 52) { fb = FB_WH1; KT = 8; u = s - 36; rot = r8; }
  else if (s < 68) { fb = FB_WI2; KT = 8; u = s - 52; rot = r8; }
  else             { fb = FB_WH2; KT = 8; u = s - 68; rot = r8; }
  int k = u >> 1, h = u & 1;
  int kp = (k + rot) & (KT - 1);
  __builtin_amdgcn_sched_barrier(0);
#pragma unroll
  for (int j = 0; j < 3; ++j) {
    int fg = h * 3 + j;
    int nt = (fg >> 1) * 16 + wave * 2 + (fg & 1);
    const short* g = wpack + ((size_t)fb + (size_t)(nt * KT + kp) * 64 + lane) * 8;
    __builtin_amdgcn_global_load_lds(
        (const __attribute__((address_space(1))) void*)g,
        (__attribute__((address_space(3))) void*)(ringbuf + j * 512), 16, 0, 0);
  }
  __builtin_amdgcn_sched_barrier(0);
}

// One GRU cell. SB = first sub-slice of this cell; KTGI = gi K-tiles (2 or 8).
template<int SB, int KTGI>
__device__ __forceinline__ void cell_stream(
    const short* gi_src, int gi_S, const short* gh_src,
    const short* __restrict__ wpack, short (*ring)[1536],
    float (&hm)[8], short* hb_l, const CB& cb,
    int r2, int r8, int wave, int lane, int l15, int lhi, int r0q)
{
  f32x4 z4 = {0.f, 0.f, 0.f, 0.f};
  f32x4 agi[6], agh[6];
#pragma unroll
  for (int j = 0; j < 6; ++j) { agi[j] = z4; agh[j] = z4; }

  const int rgi = (KTGI == 2) ? r2 : r8;
  // ---- gi GEMM ----
#pragma unroll
  for (int k = 0; k < KTGI; ++k) {
    int kp = (k + rgi) & (KTGI - 1);
    short8 a;
#pragma unroll
    for (int h = 0; h < 2; ++h) {
      const int s = SB + k * 2 + h;
      issue_sub(wpack, s + 3, r2, r8, wave, lane, ring[(s + 3) & 3]);
      asm volatile("s_waitcnt vmcnt(9)" ::: "memory");
      __builtin_amdgcn_sched_barrier(0);
      if (h == 0) a = lds_a(gi_src, gi_S, l15, kp * 32 + lhi * 8);
      const short* bp = ring[s & 3] + lane * 8;
#pragma unroll
      for (int j = 0; j < 3; ++j)
        agi[h * 3 + j] = __builtin_amdgcn_mfma_f32_16x16x32_bf16(
            a, *(const short8*)(bp + j * 512), agi[h * 3 + j], 0, 0, 0);
    }
  }
  // ---- gh GEMM ----
#pragma unroll
  for (int k = 0; k < 8; ++k) {
    int kp = (k + r8) & 7;
    short8 a;
#pragma unroll
    for (int h = 0; h < 2; ++h) {
      const int s = SB + KTGI * 2 + k * 2 + h;
      issue_sub(wpack, s + 3, r2, r8, wave, lane, ring[(s + 3) & 3]);
      asm volatile("s_waitcnt vmcnt(9)" ::: "memory");
      __builtin_amdgcn_sched_barrier(0);
      if (h == 0) a = lds_a(gh_src, 256, l15, kp * 32 + lhi * 8);
      const short* bp = ring[s & 3] + lane * 8;
#pragma unroll
      for (int j = 0; j < 3; ++j)
        agh[h * 3 + j] = __builtin_amdgcn_mfma_f32_16x16x32_bf16(
            a, *(const short8*)(bp + j * 512), agh[h * 3 + j], 0, 0, 0);
    }
  }

  block_sync_lds();  // all waves done reading old h before overwrite

#pragma unroll
  for (int tl = 0; tl < 2; ++tl) {
    int c = wave * 32 + tl * 16 + l15;
    float brz = tl ? cb.brz1 : cb.brz0;
    float bzz = tl ? cb.bzz1 : cb.bzz0;
    float bin = tl ? cb.bin1 : cb.bin0;
    float bhn = tl ? cb.bhn1 : cb.bhn0;
#pragma unroll
    for (int j = 0; j < 4; ++j) {
      int row = r0q + j;
      float r = fast_sigmoid(agi[tl][j] + agh[tl][j] + brz);
      float z = fast_sigmoid(agi[2 + tl][j] + agh[2 + tl][j] + bzz);
      float n = fast_tanh(agi[4 + tl][j] + bin + r * (agh[4 + tl][j] + bhn));
      float hold = hm[tl * 4 + j];
      float hnew = n + z * (hold - n);
      hm[tl * 4 + j] = hnew;
      hb_l[row * 256 + (c ^ ((row & 7) << 3))] = bf16_rne(hnew);
    }
  }
  block_sync_lds();  // h(new) visible to next stage
}

__global__ void pack_weights(const float* __restrict__ Wi0, const float* __restrict__ Wh0,
                             const float* __restrict__ Wih12, const float* __restrict__ Whh12,
                             const float* __restrict__ W1, const float* __restrict__ W2,
                             short* __restrict__ outp)
{
  int f = blockIdx.x * blockDim.x + threadIdx.x;
  if (f >= TOTAL_FRAGS) return;
  const float* src; int K; int rel;
  if (f < FB_WH0)        { src = Wi0;            K = 64;  rel = f; }
  else if (f < FB_WI1)   { src = Wh0;            K = 256; rel = f - FB_WH0; }
  else if (f < FB_WH1)   { src = Wih12;          K = 256; rel = f - FB_WI1; }
  else if (f < FB_WI2)   { src = Whh12;          K = 256; rel = f - FB_WH1; }
  else if (f < FB_WH2)   { src = Wih12 + 196608; K = 256; rel = f - FB_WI2; }
  else if (f < FB_W1)    { src = Whh12 + 196608; K = 256; rel = f - FB_WH2; }
  else if (f < FB_W2)    { src = W1;             K = 256; rel = f - FB_W1; }
  else                   { src = W2;             K = 256; rel = f - FB_W2; }
  int lane = rel & 63;
  int q = rel >> 6;
  int KT = K >> 5;
  int kt = q % KT;
  int nt = q / KT;
  int n  = nt * 16 + (lane & 15);
  int k0 = kt * 32 + (lane >> 4) * 8;
  short8 v;
#pragma unroll
  for (int e = 0; e < 8; ++e) v[e] = bf16_rne(src[(size_t)n * K + k0 + e]);
  *(short8*)(outp + (size_t)f * 8) = v;
}

__global__ __launch_bounds__(NTHR, 2)
void timegan_main(const float* __restrict__ noise,
                  const short* __restrict__ wpack,
                  const float* __restrict__ b_ih0, const float* __restrict__ b_hh0,
                  const float* __restrict__ b_ih12, const float* __restrict__ b_hh12,
                  const float* __restrict__ b1v, const float* __restrict__ b2v,
                  float* __restrict__ out)
{
  __shared__ __align__(16) short wring[8][4][1536];   // 96 KB, 4-deep/wave
  __shared__ __align__(16) short xbuf[BQ * 64];
  __shared__ __align__(16) short hbuf0[BQ * 256];
  __shared__ __align__(16) short hbuf1[BQ * 256];
  __shared__ __align__(16) short hbuf2[BQ * 256];
  __shared__ __align__(16) short abuf[BQ * 256];
  __shared__ __align__(16) float ybuf[BQ * 64];

  const int tid = threadIdx.x;
  const int lane = tid & 63, wave = tid >> 6;
  const int l15 = lane & 15, lhi = lane >> 4, r0q = lhi * 4;
  const int brow = blockIdx.x * BQ;
  const int r8 = blockIdx.x & 7;     // per-block kt rotation (KT=8 GEMMs)
  const int r2 = blockIdx.x & 1;     // per-block kt rotation (KT=2 GEMM)

  float hm0[8], hm1[8], hm2[8];
#pragma unroll
  for (int j = 0; j < 8; ++j) { hm0[j] = 0.f; hm1[j] = 0.f; hm2[j] = 0.f; }

  for (int i = tid; i < BQ * 256; i += NTHR) {
    hbuf0[i] = 0; hbuf1[i] = 0; hbuf2[i] = 0;
  }
  for (int i = tid; i < BQ * 64; i += NTHR) {
    int r = i >> 6, c = i & 63;
    xbuf[r * 64 + (c ^ ((r & 7) << 3))] = bf16_rne(noise[(size_t)(brow + r) * 64 + c]);
  }

  CB cb0 = make_cb(b_ih0, b_hh0, wave, l15);
  CB cb1 = make_cb(b_ih12, b_hh12, wave, l15);
  CB cb2 = make_cb(b_ih12 + 768, b_hh12 + 768, wave, l15);
  float bm1_0 = b1v[wave * 32 + l15];
  float bm1_1 = b1v[wave * 32 + 16 + l15];
  float bm2 = (wave < 4) ? b2v[wave * 16 + l15] : 0.f;

  // persistent register weights: MLP1 (16 frags) + MLP2 (8 frags, waves 0-3)
  short8 m1[16];
#pragma unroll
  for (int kt = 0; kt < 8; ++kt) {
    m1[kt * 2]     = *B_ADDR(FB_W1, wave * 2,     kt, 8);
    m1[kt * 2 + 1] = *B_ADDR(FB_W1, wave * 2 + 1, kt, 8);
  }
  short8 m2[8];
  if (wave < 4) {
#pragma unroll
    for (int kt = 0; kt < 8; ++kt) m2[kt] = *B_ADDR(FB_W2, wave, kt, 8);
  }

  // drain init-time vmem so the counted-vmcnt stream starts clean
  asm volatile("s_waitcnt vmcnt(0)" ::: "memory");
  __builtin_amdgcn_sched_barrier(0);
  block_sync_lds();

  // prologue: 3 sub-slices in flight
  issue_sub(wpack, 0, r2, r8, wave, lane, wring[wave][0]);
  issue_sub(wpack, 1, r2, r8, wave, lane, wring[wave][1]);
  issue_sub(wpack, 2, r2, r8, wave, lane, wring[wave][2]);

#pragma unroll 1
  for (int t = 0; t < TT; ++t) {
    cell_stream<0, 2>(xbuf, 64,   hbuf0, wpack, wring[wave], hm0, hbuf0, cb0,
                      r2, r8, wave, lane, l15, lhi, r0q);
    cell_stream<20, 8>(hbuf0, 256, hbuf1, wpack, wring[wave], hm1, hbuf1, cb1,
                       r2, r8, wave, lane, l15, lhi, r0q);
    cell_stream<52, 8>(hbuf1, 256, hbuf2, wpack, wring[wave], hm2, hbuf2, cb2,
                       r2, r8, wave, lane, l15, lhi, r0q);

    // ---- MLP1: a1 = relu(h2 @ W1^T + b1), weights in registers ----
    f32x4 z4 = {0.f, 0.f, 0.f, 0.f};
    f32x4 am[2]; am[0] = z4; am[1] = z4;
#pragma unroll
    for (int kt = 0; kt < 8; ++kt) {
      short8 a = lds_a(hbuf2, 256, l15, kt * 32 + lhi * 8);
      am[0] = __builtin_amdgcn_mfma_f32_16x16x32_bf16(a, m1[kt * 2],     am[0], 0, 0, 0);
      am[1] = __builtin_amdgcn_mfma_f32_16x16x32_bf16(a, m1[kt * 2 + 1], am[1], 0, 0, 0);
    }
#pragma unroll
    for (int tl = 0; tl < 2; ++tl) {
      int c = wave * 32 + tl * 16 + l15;
      float bb = tl ? bm1_1 : bm1_0;
#pragma unroll
      for (int j = 0; j < 4; ++j) {
        int row = r0q + j;
        float v = fmaxf(am[tl][j] + bb, 0.f);
        abuf[row * 256 + (c ^ ((row & 7) << 3))] = bf16_rne(v);
      }
    }
    block_sync_lds();

    // ---- MLP2: y = tanh(a1 @ W2^T + b2), weights in registers ----
    if (wave < 4) {
      f32x4 ay = z4;
#pragma unroll
      for (int kt = 0; kt < 8; ++kt) {
        short8 a = lds_a(abuf, 256, l15, kt * 32 + lhi * 8);
        ay = __builtin_amdgcn_mfma_f32_16x16x32_bf16(a, m2[kt], ay, 0, 0, 0);
      }
      int c = wave * 16 + l15;
#pragma unroll
      for (int j = 0; j < 4; ++j) {
        int row = r0q + j;
        float y = fast_tanh(ay[j] + bm2);
        ybuf[row * 64 + c] = y;
        xbuf[row * 64 + (c ^ ((row & 7) << 3))] = bf16_rne(y);  // feedback
      }
    }
    block_sync_lds();

    // ---- store y(t): wave w stores rows 2w, 2w+1 as full 256B rows ----
    {
      int r0 = wave * 2;
      size_t base = ((size_t)(brow + r0) * TT + t) * 64;
      out[base + lane] = ybuf[r0 * 64 + lane];
      out[base + (size_t)TT * 64 + lane] = ybuf[(r0 + 1) * 64 + lane];
    }
  }

  // drain the over-issued prefetch before wave exit
  asm volatile("s_waitcnt vmcnt(0)" ::: "memory");
}

extern "C" void kernel_launch(void* const* d_in, const int* in_sizes, int n_in,
                              void* d_out, int out_size, void* d_ws, size_t ws_size,
                              hipStream_t stream)
{
  const float* noise  = (const float*)d_in[0];
  const float* W_ih0  = (const float*)d_in[1];
  const float* W_hh0  = (const float*)d_in[2];
  const float* b_ih0  = (const float*)d_in[3];
  const float* b_hh0  = (const float*)d_in[4];
  const float* W_ih12 = (const float*)d_in[5];
  const float* W_hh12 = (const float*)d_in[6];
  const float* b_ih12 = (const float*)d_in[7];
  const float* b_hh12 = (const float*)d_in[8];
  const float* W1     = (const float*)d_in[9];
  const float* b1     = (const float*)d_in[10];
  const float* W2     = (const float*)d_in[11];
  const float* b2     = (const float*)d_in[12];
  float* out   = (float*)d_out;
  short* wpack = (short*)d_ws;   // 2,228,224 bytes of bf16 packed weights

  pack_weights<<<(TOTAL_FRAGS + 255) / 256, 256, 0, stream>>>(
      W_ih0, W_hh0, W_ih12, W_hh12, W1, W2, wpack);
  timegan_main<<<NBLK, NTHR, 0, stream>>>(
      noise, wpack, b_ih0, b_hh0, b_ih12, b_hh12, b1, b2, out);
}